// Round 19
// baseline (196.149 us; speedup 1.0000x reference)
//
#include <hip/hip_runtime.h>
#include <stdint.h>

typedef __attribute__((ext_vector_type(8))) short short8;
typedef __attribute__((ext_vector_type(8))) unsigned short u16x8;
typedef __attribute__((ext_vector_type(4))) float f32x4;

#define DEV static __device__ __forceinline__

DEV unsigned short f2bf(float f) {
  unsigned u = __builtin_bit_cast(unsigned, f);
  u += 0x7FFF + ((u >> 16) & 1);
  return (unsigned short)(u >> 16);
}

DEV unsigned cvtpk_bf16(float lo, float hi) {
  unsigned r;
  asm("v_cvt_pk_bf16_f32 %0, %1, %2" : "=v"(r) : "v"(lo), "v"(hi));
  return r;
}

#define GLOAD16(gptr, lptr)                                                        \
  __builtin_amdgcn_global_load_lds((const __attribute__((address_space(1))) void*)(gptr), \
                                   (__attribute__((address_space(3))) void*)(lptr), 16, 0, 0)

// ---------------- prep: cast x (blocks 0..4095) + transpose-cast W (blocks 4096..5119) ----
__global__ __launch_bounds__(256) void k_prep(const float* __restrict__ x,
                                              const float* __restrict__ wq,
                                              const float* __restrict__ wk,
                                              const float* __restrict__ wv,
                                              const float* __restrict__ wo,
                                              unsigned short* __restrict__ xb,
                                              unsigned short* __restrict__ wqkvT,
                                              unsigned short* __restrict__ woT) {
  __shared__ __align__(16) unsigned short t[64 * 72];
  const int bid = blockIdx.x;
  const int tid = threadIdx.x;
  if (bid < 4096) {
    int idx = (bid * 256 + tid) * 8;
    float4 a = *(const float4*)(x + idx);
    float4 b = *(const float4*)(x + idx + 4);
    u16x8 v;
    v[0] = f2bf(a.x); v[1] = f2bf(a.y); v[2] = f2bf(a.z); v[3] = f2bf(a.w);
    v[4] = f2bf(b.x); v[5] = f2bf(b.y); v[6] = f2bf(b.z); v[7] = f2bf(b.w);
    *(u16x8*)(xb + idx) = v;
    return;
  }
  const int tt = bid - 4096;
  const int z = tt >> 8;
  const int r0 = ((tt >> 4) & 15) * 64;
  const int c0 = (tt & 15) * 64;
  const float* src = (z == 0) ? wq : (z == 1) ? wk : (z == 2) ? wv : wo;
  unsigned short* dst = (z < 3) ? (wqkvT + (size_t)z * 1048576) : woT;
#pragma unroll
  for (int it = 0; it < 4; ++it) {
    int idx = it * 256 + tid;
    int il = idx >> 4;
    int c4 = idx & 15;
    float4 v = *(const float4*)(src + (size_t)(r0 + il) * 1024 + c0 + c4 * 4);
    t[(c4 * 4 + 0) * 72 + il] = f2bf(v.x);
    t[(c4 * 4 + 1) * 72 + il] = f2bf(v.y);
    t[(c4 * 4 + 2) * 72 + il] = f2bf(v.z);
    t[(c4 * 4 + 3) * 72 + il] = f2bf(v.w);
  }
  __syncthreads();
#pragma unroll
  for (int it = 0; it < 2; ++it) {
    int idx = it * 256 + tid;
    int ol = idx >> 3;
    int ch = idx & 7;
    *(u16x8*)(dst + (size_t)(c0 + ol) * 1024 + r0 + ch * 8) =
        *(const u16x8*)(t + ol * 72 + ch * 8);
  }
}

// ---------------- QKV GEMM: 128x256 tile, 8 waves (2Mx4N), 64x64x4 per wave ----------------
// C[8192][3072] = xb * wqkvT^T; z = global col>>10 selects Q/K/V (256-wide n-tiles
// never cross z boundaries). 32 MFMA per K-step per wave from 16 ds_read_b128 --
// halves per-MFMA LDS+barrier cost vs 128x128 (same lever as attn r11).
// Grid 768 = 64m x 12n, tail-free (3 blocks/CU rounds); n-major XCD chunking.
__global__ __launch_bounds__(512) void k_qkv(const unsigned short* __restrict__ A,
                                             const unsigned short* __restrict__ Bt,
                                             unsigned short* __restrict__ outQK,
                                             unsigned short* __restrict__ vTout) {
  __shared__ __align__(16) unsigned short sA[128 * 64];
  __shared__ __align__(16) unsigned short sB[256 * 64];
  const int tid = threadIdx.x;
  const int l = tid & 63, w = tid >> 6;  // 8 waves
  const int wm = (w >> 2) * 64;          // 2 M-halves
  const int wn = (w & 3) * 64;           // 4 N-quarters
  const int q16 = l & 15, g4 = l >> 4;
  const int lrow = l >> 3;
  const int lsw = ((l & 7) ^ lrow) * 8;  // pre-swizzled k-offset (elems)

  // XCD-bijective chunked swizzle, n-major: each XCD gets 96 consecutive swz
  // = 1.5 B-panels + full A sweep (A fetched once per XCD).
  const int lid = blockIdx.x;
  const int swz = (lid & 7) * 96 + (lid >> 3);
  const int ntile = swz >> 6;          // 0..11
  const int m0 = (swz & 63) * 128;
  const int n0g = ntile * 256;         // global col base
  const int z = n0g >> 10;
  const int n0 = n0g & 1023;           // col base within the z-matrix
  const unsigned short* bt = Bt + (size_t)z * 1048576;
  unsigned short* dst = outQK + (size_t)z * 8388608;
  const float sc = (z == 0) ? 0.125f * 1.44269504088896f : 1.0f;

  f32x4 acc[4][4];
#pragma unroll
  for (int i = 0; i < 4; ++i)
#pragma unroll
    for (int j = 0; j < 4; ++j) acc[i][j] = (f32x4){0.f, 0.f, 0.f, 0.f};

  for (int k0 = 0; k0 < 1024; k0 += 64) {
    __syncthreads();
    // 48 chunks (16 A + 32 B) over 8 waves: 6 per wave; chunk covers 8 rows
#pragma unroll
    for (int r = 0; r < 6; ++r) {
      int chunk = w * 6 + r;
      if (chunk < 16) {
        int row = chunk * 8 + lrow;
        GLOAD16(A + (size_t)(m0 + row) * 1024 + k0 + lsw, sA + chunk * 512);
      } else {
        int row = (chunk - 16) * 8 + lrow;
        GLOAD16(bt + (size_t)(n0 + row) * 1024 + k0 + lsw, sB + (chunk - 16) * 512);
      }
    }
    __syncthreads();
#pragma unroll
    for (int kk = 0; kk < 2; ++kk) {
      short8 af[4], bf_[4];
#pragma unroll
      for (int i = 0; i < 4; ++i) {
        int ra = wm + i * 16 + q16;
        af[i] = *(const short8*)(sA + ra * 64 + (((kk * 4 + g4) ^ (ra & 7)) * 8));
        int rb = wn + i * 16 + q16;
        bf_[i] = *(const short8*)(sB + rb * 64 + (((kk * 4 + g4) ^ (rb & 7)) * 8));
      }
#pragma unroll
      for (int mi = 0; mi < 4; ++mi)
#pragma unroll
        for (int ni = 0; ni < 4; ++ni)
          acc[mi][ni] =
              __builtin_amdgcn_mfma_f32_16x16x32_bf16(af[mi], bf_[ni], acc[mi][ni], 0, 0, 0);
    }
  }

  if (z == 2) {
    // V: write transposed vT[((b*16+h)*64+d)*2048 + seq], 4 consecutive seq per store
#pragma unroll
    for (int mi = 0; mi < 4; ++mi) {
#pragma unroll
      for (int ni = 0; ni < 4; ++ni) {
        int row0 = m0 + wm + mi * 16 + g4 * 4;
        int col = n0 + wn + ni * 16 + q16;
        int b = row0 >> 11, seq0 = row0 & 2047;
        int h = col >> 6, d = col & 63;
        uint2 pv;
        pv.x = cvtpk_bf16(acc[mi][ni][0], acc[mi][ni][1]);
        pv.y = cvtpk_bf16(acc[mi][ni][2], acc[mi][ni][3]);
        *(uint2*)(vTout + (((size_t)(b * 16 + h) * 64 + d) * 2048 + seq0)) = pv;
      }
    }
  } else {
#pragma unroll
    for (int mi = 0; mi < 4; ++mi) {
#pragma unroll
      for (int ni = 0; ni < 4; ++ni) {
#pragma unroll
        for (int j = 0; j < 4; ++j) {
          int row = m0 + wm + mi * 16 + g4 * 4 + j;
          int col = n0 + wn + ni * 16 + q16;
          int b = row >> 11, seq = row & 2047;
          int h = col >> 6, d = col & 63;
          dst[((((size_t)b * 16 + h) * 2048 + seq) << 6) + d] = f2bf(acc[mi][ni][j] * sc);
        }
      }
    }
  }
}

// ---------------- out-proj GEMM (128x128, bias add, f32 out), XCD-chunked ----------------
__global__ __launch_bounds__(256) void k_gemmO(const unsigned short* __restrict__ A,
                                               const unsigned short* __restrict__ Bt,
                                               float* __restrict__ outF,
                                               const float* __restrict__ bias) {
  __shared__ __align__(16) unsigned short sA[128 * 64];
  __shared__ __align__(16) unsigned short sB[128 * 64];
  const int tid = threadIdx.x;
  const int l = tid & 63;
  const int w = tid >> 6;

  const int lid = blockIdx.x;
  const int swz = (lid & 7) * 64 + (lid >> 3);
  const int m0 = (swz >> 3) * 128;
  const int n0 = (swz & 7) * 128;

  const int wm = (w >> 1) * 64;
  const int wn = (w & 1) * 64;
  const int q16 = l & 15, g4 = l >> 4;
  const int lrow = l >> 3;
  const int lsw = ((l & 7) ^ lrow) * 8;

  f32x4 acc[4][4];
#pragma unroll
  for (int i = 0; i < 4; ++i)
#pragma unroll
    for (int j = 0; j < 4; ++j) acc[i][j] = (f32x4){0.f, 0.f, 0.f, 0.f};

  for (int k0 = 0; k0 < 1024; k0 += 64) {
    __syncthreads();
#pragma unroll
    for (int r = 0; r < 4; ++r) {
      int chunk = w * 4 + r;
      int row = chunk * 8 + lrow;
      GLOAD16(A + (size_t)(m0 + row) * 1024 + k0 + lsw, sA + chunk * 512);
      GLOAD16(Bt + (size_t)(n0 + row) * 1024 + k0 + lsw, sB + chunk * 512);
    }
    __syncthreads();
#pragma unroll
    for (int kk = 0; kk < 2; ++kk) {
      short8 af[4], bf_[4];
#pragma unroll
      for (int i = 0; i < 4; ++i) {
        int ra = wm + i * 16 + q16;
        af[i] = *(const short8*)(sA + ra * 64 + (((kk * 4 + g4) ^ (ra & 7)) * 8));
        int rb = wn + i * 16 + q16;
        bf_[i] = *(const short8*)(sB + rb * 64 + (((kk * 4 + g4) ^ (rb & 7)) * 8));
      }
#pragma unroll
      for (int mi = 0; mi < 4; ++mi)
#pragma unroll
        for (int ni = 0; ni < 4; ++ni)
          acc[mi][ni] =
              __builtin_amdgcn_mfma_f32_16x16x32_bf16(af[mi], bf_[ni], acc[mi][ni], 0, 0, 0);
    }
  }

#pragma unroll
  for (int mi = 0; mi < 4; ++mi) {
#pragma unroll
    for (int ni = 0; ni < 4; ++ni) {
#pragma unroll
      for (int j = 0; j < 4; ++j) {
        int row = m0 + wm + mi * 16 + g4 * 4 + j;
        int col = n0 + wn + ni * 16 + q16;
        outF[(size_t)row * 1024 + col] = acc[mi][ni][j] + bias[col];
      }
    }
  }
}

// ---------------- flash attention: Q,K [bh][2048][64], Vt [bh][64][2048] bf16 ----------------
// (r14/r16-proven version, untouched)
__global__ __launch_bounds__(512, 4) void k_attn(const unsigned short* __restrict__ Q,
                                                 const unsigned short* __restrict__ Kg,
                                                 const unsigned short* __restrict__ Vt,
                                                 unsigned short* __restrict__ Oo) {
  __shared__ __align__(16) unsigned short sK[2][64 * 64];    // [key][d] swizzled, dbuf
  __shared__ __align__(16) unsigned short sV[2][64 * 64];    // [d][key] swizzled, dbuf
  __shared__ __align__(16) unsigned short sPa[8][16 * 64];   // per-wave P, q-group a
  __shared__ __align__(16) unsigned short sPb[8][16 * 64];   // per-wave P, q-group b
  const int tid = threadIdx.x;
  const int l = tid & 63, w = tid >> 6;  // w in 0..7
  const int q16 = l & 15, g = l >> 4;
  const int lrow = l >> 3;
  const int lsw = ((l & 7) ^ lrow) * 8;

  const int bid = blockIdx.x;
  const int swz = (bid & 7) * 64 + (bid >> 3);
  const int bh = swz >> 3;
  const int q0 = (swz & 7) * 256 + w * 32;

  const unsigned short* Qb = Q + ((size_t)bh * 2048 + q0) * 64;
  const unsigned short* Kb = Kg + (size_t)bh * 2048 * 64;
  const unsigned short* Vb = Vt + (size_t)bh * 64 * 2048;

  short8 qfa[2], qfb[2];
#pragma unroll
  for (int s = 0; s < 2; ++s) {
    qfa[s] = *(const short8*)(Qb + q16 * 64 + s * 32 + g * 8);
    qfb[s] = *(const short8*)(Qb + (16 + q16) * 64 + s * 32 + g * 8);
  }

  float suma = 0.f, sumb = 0.f;
  f32x4 oa[4], ob[4];
#pragma unroll
  for (int dt = 0; dt < 4; ++dt) {
    oa[dt] = (f32x4){0.f, 0.f, 0.f, 0.f};
    ob[dt] = (f32x4){0.f, 0.f, 0.f, 0.f};
  }

  auto STAGE = [&](int buf, int kv) {
    int row = w * 8 + lrow;
    GLOAD16(Kb + (size_t)(kv + row) * 64 + lsw, &sK[buf][w * 512]);
    GLOAD16(Vb + (size_t)row * 2048 + kv + lsw, &sV[buf][w * 512]);
  };

  STAGE(0, 0);
  asm volatile("s_waitcnt vmcnt(0)" ::: "memory");
  __syncthreads();

  for (int ti = 0; ti < 32; ++ti) {
    const int cur = ti & 1;
    if (ti < 31) STAGE(cur ^ 1, (ti + 1) * 64);

    f32x4 sta[4], stb[4];
    __builtin_amdgcn_s_setprio(1);
#pragma unroll
    for (int t = 0; t < 4; ++t) {
      sta[t] = (f32x4){0.f, 0.f, 0.f, 0.f};
      stb[t] = (f32x4){0.f, 0.f, 0.f, 0.f};
#pragma unroll
      for (int s = 0; s < 2; ++s) {
        int key = t * 16 + q16;
        short8 kf = *(const short8*)(&sK[cur][key * 64 + (((s * 4 + g) ^ (key & 7)) * 8)]);
        sta[t] = __builtin_amdgcn_mfma_f32_16x16x32_bf16(kf, qfa[s], sta[t], 0, 0, 0);
        stb[t] = __builtin_amdgcn_mfma_f32_16x16x32_bf16(kf, qfb[s], stb[t], 0, 0, 0);
      }
    }
    __builtin_amdgcn_s_setprio(0);

    float pa[4][4], pb[4][4];
    float psa = 0.f, psb = 0.f;
#pragma unroll
    for (int t = 0; t < 4; ++t)
#pragma unroll
      for (int j = 0; j < 4; ++j) {
        pa[t][j] = __builtin_amdgcn_exp2f(sta[t][j]);
        psa += pa[t][j];
        pb[t][j] = __builtin_amdgcn_exp2f(stb[t][j]);
        psb += pb[t][j];
      }
    psa += __shfl_xor(psa, 16);
    psa += __shfl_xor(psa, 32);
    psb += __shfl_xor(psb, 16);
    psb += __shfl_xor(psb, 32);
    suma += psa;
    sumb += psb;

#pragma unroll
    for (int t = 0; t < 4; ++t) {
      int c16 = t * 2 + (g >> 1);
      int off = q16 * 64 + ((c16 ^ (q16 & 7)) * 8) + (g & 1) * 4;
      uint2 pv;
      pv.x = cvtpk_bf16(pa[t][0], pa[t][1]);
      pv.y = cvtpk_bf16(pa[t][2], pa[t][3]);
      *(uint2*)(&sPa[w][off]) = pv;
      pv.x = cvtpk_bf16(pb[t][0], pb[t][1]);
      pv.y = cvtpk_bf16(pb[t][2], pb[t][3]);
      *(uint2*)(&sPb[w][off]) = pv;
    }
    asm volatile("s_waitcnt lgkmcnt(0)" ::: "memory");
    __builtin_amdgcn_sched_barrier(0);

    __builtin_amdgcn_s_setprio(1);
#pragma unroll
    for (int win = 0; win < 2; ++win) {
      int poff = q16 * 64 + (((win * 4 + g) ^ (q16 & 7)) * 8);
      short8 pfa = *(const short8*)(&sPa[w][poff]);
      short8 pfb = *(const short8*)(&sPb[w][poff]);
#pragma unroll
      for (int dt = 0; dt < 4; ++dt) {
        int d = dt * 16 + q16;
        short8 vf = *(const short8*)(&sV[cur][d * 64 + (((win * 4 + g) ^ (d & 7)) * 8)]);
        oa[dt] = __builtin_amdgcn_mfma_f32_16x16x32_bf16(pfa, vf, oa[dt], 0, 0, 0);
        ob[dt] = __builtin_amdgcn_mfma_f32_16x16x32_bf16(pfb, vf, ob[dt], 0, 0, 0);
      }
    }
    __builtin_amdgcn_s_setprio(0);

    asm volatile("s_waitcnt vmcnt(0)" ::: "memory");
    __syncthreads();
  }

  float inva = 1.0f / suma, invb = 1.0f / sumb;
  int b = bh >> 4, h = bh & 15;
#pragma unroll
  for (int j = 0; j < 4; ++j) {
    float ija = __shfl(inva, g * 4 + j);
    float ijb = __shfl(invb, g * 4 + j);
#pragma unroll
    for (int dt = 0; dt < 4; ++dt) {
      sPa[w][(g * 4 + j) * 64 + dt * 16 + q16] = f2bf(oa[dt][j] * ija);
      sPb[w][(g * 4 + j) * 64 + dt * 16 + q16] = f2bf(ob[dt][j] * ijb);
    }
  }
  unsigned short* Ob = Oo + ((size_t)b * 2048 + q0) * 1024 + h * 64;
#pragma unroll
  for (int it = 0; it < 4; ++it) {
    int flat = it * 512 + l * 8;
    int r = flat >> 6, c = flat & 63;
    const unsigned short* src = (it < 2) ? &sPa[w][r * 64 + c] : &sPb[w][(r - 16) * 64 + c];
    *(u16x8*)(Ob + (size_t)r * 1024 + c) = *(const u16x8*)src;
  }
}

extern "C" void kernel_launch(void* const* d_in, const int* in_sizes, int n_in,
                              void* d_out, int out_size, void* d_ws, size_t ws_size,
                              hipStream_t stream) {
  const float* x = (const float*)d_in[0];
  const float* Wq = (const float*)d_in[1];
  const float* Wk = (const float*)d_in[2];
  const float* Wv = (const float*)d_in[3];
  const float* Wo = (const float*)d_in[4];
  const float* bo = (const float*)d_in[5];
  float* out = (float*)d_out;
  char* ws = (char*)d_ws;

  // workspace layout (bytes)
  unsigned short* xb    = (unsigned short*)(ws);               // 8192x1024 bf16 (16MB)
  unsigned short* wqkvT = (unsigned short*)(ws + 16777216);    // 3x1024x1024 (6MB)
  unsigned short* woT   = (unsigned short*)(ws + 23068672);    // 1024x1024 (2MB)
  unsigned short* qkv   = (unsigned short*)(ws + 25165824);    // Q,K: 2 x [64][2048][64]
  unsigned short* vT    = (unsigned short*)(ws + 75497472);    // [64][64][2048] (16MB)
  unsigned short* aout  = xb;  // reuse: xb dead after QKV GEMM

  k_prep<<<5120, 256, 0, stream>>>(x, Wq, Wk, Wv, Wo, xb, wqkvT, woT);
  k_qkv<<<768, 512, 0, stream>>>(xb, wqkvT, qkv, vT);
  k_attn<<<512, 512, 0, stream>>>(qkv, qkv + 8388608, vT, aout);
  k_gemmO<<<512, 256, 0, stream>>>(aout, woT, out, bo);
}

// Round 20
// 187.406 us; speedup vs baseline: 1.0467x; 1.0467x over previous
//
#include <hip/hip_runtime.h>
#include <stdint.h>

typedef __attribute__((ext_vector_type(8))) short short8;
typedef __attribute__((ext_vector_type(8))) unsigned short u16x8;
typedef __attribute__((ext_vector_type(4))) float f32x4;

#define DEV static __device__ __forceinline__

DEV unsigned short f2bf(float f) {
  unsigned u = __builtin_bit_cast(unsigned, f);
  u += 0x7FFF + ((u >> 16) & 1);
  return (unsigned short)(u >> 16);
}

DEV unsigned cvtpk_bf16(float lo, float hi) {
  unsigned r;
  asm("v_cvt_pk_bf16_f32 %0, %1, %2" : "=v"(r) : "v"(lo), "v"(hi));
  return r;
}

#define GLOAD16(gptr, lptr)                                                        \
  __builtin_amdgcn_global_load_lds((const __attribute__((address_space(1))) void*)(gptr), \
                                   (__attribute__((address_space(3))) void*)(lptr), 16, 0, 0)

// ---------------- prep: cast x (blocks 0..4095) + transpose-cast W (blocks 4096..5119) ----
// Fused single launch: cast blocks and transW blocks run concurrently.
__global__ __launch_bounds__(256) void k_prep(const float* __restrict__ x,
                                              const float* __restrict__ wq,
                                              const float* __restrict__ wk,
                                              const float* __restrict__ wv,
                                              const float* __restrict__ wo,
                                              unsigned short* __restrict__ xb,
                                              unsigned short* __restrict__ wqkvT,
                                              unsigned short* __restrict__ woT) {
  __shared__ __align__(16) unsigned short t[64 * 72];
  const int bid = blockIdx.x;
  const int tid = threadIdx.x;
  if (bid < 4096) {
    // cast x: fp32 -> bf16, 8 elems/thread, manual RNE
    int idx = (bid * 256 + tid) * 8;
    float4 a = *(const float4*)(x + idx);
    float4 b = *(const float4*)(x + idx + 4);
    u16x8 v;
    v[0] = f2bf(a.x); v[1] = f2bf(a.y); v[2] = f2bf(a.z); v[3] = f2bf(a.w);
    v[4] = f2bf(b.x); v[5] = f2bf(b.y); v[6] = f2bf(b.z); v[7] = f2bf(b.w);
    *(u16x8*)(xb + idx) = v;
    return;
  }
  // transW: [1024][1024] f32 -> Wt [o][i] bf16
  const int tt = bid - 4096;
  const int z = tt >> 8;
  const int r0 = ((tt >> 4) & 15) * 64;  // input row (i)
  const int c0 = (tt & 15) * 64;         // input col (o)
  const float* src = (z == 0) ? wq : (z == 1) ? wk : (z == 2) ? wv : wo;
  unsigned short* dst = (z < 3) ? (wqkvT + (size_t)z * 1048576) : woT;
#pragma unroll
  for (int it = 0; it < 4; ++it) {
    int idx = it * 256 + tid;
    int il = idx >> 4;   // 0..63
    int c4 = idx & 15;   // float4 group
    float4 v = *(const float4*)(src + (size_t)(r0 + il) * 1024 + c0 + c4 * 4);
    t[(c4 * 4 + 0) * 72 + il] = f2bf(v.x);
    t[(c4 * 4 + 1) * 72 + il] = f2bf(v.y);
    t[(c4 * 4 + 2) * 72 + il] = f2bf(v.z);
    t[(c4 * 4 + 3) * 72 + il] = f2bf(v.w);
  }
  __syncthreads();
#pragma unroll
  for (int it = 0; it < 2; ++it) {
    int idx = it * 256 + tid;
    int ol = idx >> 3;  // 0..63 (output row = o)
    int ch = idx & 7;
    *(u16x8*)(dst + (size_t)(c0 + ol) * 1024 + r0 + ch * 8) =
        *(const u16x8*)(t + ol * 72 + ch * 8);
  }
}

// ---------------- 128x128 MFMA GEMM, A[M][1024] bf16, Bt[N][1024] bf16 ----------------
// MODE 0: QKV (z selects matrix; z=0 Q scaled -> [bh][seq][64]; z=1 K; z=2 V -> vT transposed).
// MODE 1: out-proj (bias add, f32 out)
// XCD-chunked block swizzle. 256-thread blocks, 6 blocks/CU: block-interleave
// at barriers is the pipeline (r19 lesson: fewer/fatter blocks regress).
template <int MODE>
__global__ __launch_bounds__(256) void k_gemm(const unsigned short* __restrict__ A,
                                              const unsigned short* __restrict__ Bt,
                                              unsigned short* __restrict__ outB,
                                              unsigned short* __restrict__ vTout,
                                              float* __restrict__ outF,
                                              const float* __restrict__ bias) {
  __shared__ __align__(16) unsigned short sA[128 * 64];
  __shared__ __align__(16) unsigned short sB[128 * 64];
  const int tid = threadIdx.x;
  const int l = tid & 63;
  const int w = tid >> 6;

  // XCD-bijective chunked swizzle (nwg % 8 == 0 for both modes)
  const int lid = blockIdx.x;
  const int nwg = (MODE == 0) ? 1536 : 512;
  const int swz = (lid & 7) * (nwg >> 3) + (lid >> 3);
  const int z = (MODE == 0) ? (swz >> 9) : 0;
  const int rem = (MODE == 0) ? (swz & 511) : swz;
  const int m0 = (rem >> 3) * 128;
  const int n0 = (rem & 7) * 128;

  const int wm = (w >> 1) * 64;
  const int wn = (w & 1) * 64;
  const int q16 = l & 15, g4 = l >> 4;
  const int lrow = l >> 3;
  const int lsw = ((l & 7) ^ lrow) * 8;  // pre-swizzled k-offset (elems)

  const unsigned short* bt = Bt + (size_t)z * 1048576;
  unsigned short* dst = outB + (size_t)z * 8388608;
  // Q pre-scaled by SCALE * log2(e) so attention can use raw v_exp_f32 (exp2)
  const float sc = (MODE == 0 && z == 0) ? 0.125f * 1.44269504088896f : 1.0f;

  f32x4 acc[4][4];
#pragma unroll
  for (int i = 0; i < 4; ++i)
#pragma unroll
    for (int j = 0; j < 4; ++j) acc[i][j] = (f32x4){0.f, 0.f, 0.f, 0.f};

  for (int k0 = 0; k0 < 1024; k0 += 64) {
    __syncthreads();
#pragma unroll
    for (int r = 0; r < 4; ++r) {
      int chunk = w * 4 + r;
      int row = chunk * 8 + lrow;
      GLOAD16(A + (size_t)(m0 + row) * 1024 + k0 + lsw, sA + chunk * 512);
      GLOAD16(bt + (size_t)(n0 + row) * 1024 + k0 + lsw, sB + chunk * 512);
    }
    __syncthreads();
#pragma unroll
    for (int kk = 0; kk < 2; ++kk) {
      short8 af[4], bf_[4];
#pragma unroll
      for (int i = 0; i < 4; ++i) {
        int ra = wm + i * 16 + q16;
        af[i] = *(const short8*)(sA + ra * 64 + (((kk * 4 + g4) ^ (ra & 7)) * 8));
        int rb = wn + i * 16 + q16;
        bf_[i] = *(const short8*)(sB + rb * 64 + (((kk * 4 + g4) ^ (rb & 7)) * 8));
      }
#pragma unroll
      for (int mi = 0; mi < 4; ++mi)
#pragma unroll
        for (int ni = 0; ni < 4; ++ni)
          acc[mi][ni] =
              __builtin_amdgcn_mfma_f32_16x16x32_bf16(af[mi], bf_[ni], acc[mi][ni], 0, 0, 0);
    }
  }

  if (MODE == 0 && z == 2) {
#pragma unroll
    for (int mi = 0; mi < 4; ++mi) {
#pragma unroll
      for (int ni = 0; ni < 4; ++ni) {
        int row0 = m0 + wm + mi * 16 + g4 * 4;
        int col = n0 + wn + ni * 16 + q16;
        int b = row0 >> 11, seq0 = row0 & 2047;
        int h = col >> 6, d = col & 63;
        uint2 pv;
        pv.x = cvtpk_bf16(acc[mi][ni][0], acc[mi][ni][1]);
        pv.y = cvtpk_bf16(acc[mi][ni][2], acc[mi][ni][3]);
        *(uint2*)(vTout + (((size_t)(b * 16 + h) * 64 + d) * 2048 + seq0)) = pv;
      }
    }
  } else {
#pragma unroll
    for (int mi = 0; mi < 4; ++mi) {
#pragma unroll
      for (int ni = 0; ni < 4; ++ni) {
#pragma unroll
        for (int j = 0; j < 4; ++j) {
          int row = m0 + wm + mi * 16 + g4 * 4 + j;
          int col = n0 + wn + ni * 16 + q16;
          float val = acc[mi][ni][j];
          if (MODE == 0) {
            val *= sc;
            int b = row >> 11, seq = row & 2047;
            int h = col >> 6, d = col & 63;
            dst[((((size_t)b * 16 + h) * 2048 + seq) << 6) + d] = f2bf(val);
          } else {
            outF[(size_t)row * 1024 + col] = val + bias[col];
          }
        }
      }
    }
  }
}

// ---------------- flash attention: Q,K [bh][2048][64], Vt [bh][64][2048] bf16 ----------------
// Q pre-scaled by SCALE*log2(e); no max-tracking. 8 waves/block, QBLK=256:
// each wave owns TWO 16-row q-groups (a/b) -> every K/V LDS fragment is loaded
// once and feeds two MFMAs; staging/barriers per q-row halved.
// bh-grouped XCD swizzle: 8 blocks of the same bh land on one XCD -> K/V L2-resident.
// LDS = 64KB -> 2 blocks/CU (grid-limited at 2 blocks/CU anyway: 512 blocks / 256 CUs).
__global__ __launch_bounds__(512, 4) void k_attn(const unsigned short* __restrict__ Q,
                                                 const unsigned short* __restrict__ Kg,
                                                 const unsigned short* __restrict__ Vt,
                                                 unsigned short* __restrict__ Oo) {
  __shared__ __align__(16) unsigned short sK[2][64 * 64];    // [key][d] swizzled, dbuf
  __shared__ __align__(16) unsigned short sV[2][64 * 64];    // [d][key] swizzled, dbuf
  __shared__ __align__(16) unsigned short sPa[8][16 * 64];   // per-wave P, q-group a
  __shared__ __align__(16) unsigned short sPb[8][16 * 64];   // per-wave P, q-group b
  const int tid = threadIdx.x;
  const int l = tid & 63, w = tid >> 6;  // w in 0..7
  const int q16 = l & 15, g = l >> 4;
  const int lrow = l >> 3;
  const int lsw = ((l & 7) ^ lrow) * 8;

  // bh-grouped XCD swizzle: 512 blocks, each XCD gets 64 consecutive swz = 8 full bh
  const int bid = blockIdx.x;
  const int swz = (bid & 7) * 64 + (bid >> 3);
  const int bh = swz >> 3;
  const int q0 = (swz & 7) * 256 + w * 32;

  const unsigned short* Qb = Q + ((size_t)bh * 2048 + q0) * 64;
  const unsigned short* Kb = Kg + (size_t)bh * 2048 * 64;
  const unsigned short* Vb = Vt + (size_t)bh * 64 * 2048;

  short8 qfa[2], qfb[2];
#pragma unroll
  for (int s = 0; s < 2; ++s) {
    qfa[s] = *(const short8*)(Qb + q16 * 64 + s * 32 + g * 8);
    qfb[s] = *(const short8*)(Qb + (16 + q16) * 64 + s * 32 + g * 8);
  }

  float suma = 0.f, sumb = 0.f;
  f32x4 oa[4], ob[4];
#pragma unroll
  for (int dt = 0; dt < 4; ++dt) {
    oa[dt] = (f32x4){0.f, 0.f, 0.f, 0.f};
    ob[dt] = (f32x4){0.f, 0.f, 0.f, 0.f};
  }

  auto STAGE = [&](int buf, int kv) {
    int row = w * 8 + lrow;
    GLOAD16(Kb + (size_t)(kv + row) * 64 + lsw, &sK[buf][w * 512]);
    GLOAD16(Vb + (size_t)row * 2048 + kv + lsw, &sV[buf][w * 512]);
  };

  STAGE(0, 0);
  asm volatile("s_waitcnt vmcnt(0)" ::: "memory");
  __syncthreads();

  for (int ti = 0; ti < 32; ++ti) {
    const int cur = ti & 1;
    if (ti < 31) STAGE(cur ^ 1, (ti + 1) * 64);  // prefetch next tile

    // S^T = K * Q^T for both q-groups; each kf loaded once, used twice
    f32x4 sta[4], stb[4];
    __builtin_amdgcn_s_setprio(1);
#pragma unroll
    for (int t = 0; t < 4; ++t) {
      sta[t] = (f32x4){0.f, 0.f, 0.f, 0.f};
      stb[t] = (f32x4){0.f, 0.f, 0.f, 0.f};
#pragma unroll
      for (int s = 0; s < 2; ++s) {
        int key = t * 16 + q16;
        short8 kf = *(const short8*)(&sK[cur][key * 64 + (((s * 4 + g) ^ (key & 7)) * 8)]);
        sta[t] = __builtin_amdgcn_mfma_f32_16x16x32_bf16(kf, qfa[s], sta[t], 0, 0, 0);
        stb[t] = __builtin_amdgcn_mfma_f32_16x16x32_bf16(kf, qfb[s], stb[t], 0, 0, 0);
      }
    }
    __builtin_amdgcn_s_setprio(0);

    // unnormalized p = exp2(score); partial sums
    float pa[4][4], pb[4][4];
    float psa = 0.f, psb = 0.f;
#pragma unroll
    for (int t = 0; t < 4; ++t)
#pragma unroll
      for (int j = 0; j < 4; ++j) {
        pa[t][j] = __builtin_amdgcn_exp2f(sta[t][j]);
        psa += pa[t][j];
        pb[t][j] = __builtin_amdgcn_exp2f(stb[t][j]);
        psb += pb[t][j];
      }
    psa += __shfl_xor(psa, 16);
    psa += __shfl_xor(psa, 32);
    psb += __shfl_xor(psb, 16);
    psb += __shfl_xor(psb, 32);
    suma += psa;
    sumb += psb;

    // pack P into per-wave LDS scratch (A-fragment layout)
#pragma unroll
    for (int t = 0; t < 4; ++t) {
      int c16 = t * 2 + (g >> 1);
      int off = q16 * 64 + ((c16 ^ (q16 & 7)) * 8) + (g & 1) * 4;
      uint2 pv;
      pv.x = cvtpk_bf16(pa[t][0], pa[t][1]);
      pv.y = cvtpk_bf16(pa[t][2], pa[t][3]);
      *(uint2*)(&sPa[w][off]) = pv;
      pv.x = cvtpk_bf16(pb[t][0], pb[t][1]);
      pv.y = cvtpk_bf16(pb[t][2], pb[t][3]);
      *(uint2*)(&sPb[w][off]) = pv;
    }
    asm volatile("s_waitcnt lgkmcnt(0)" ::: "memory");
    __builtin_amdgcn_sched_barrier(0);

    // O += P * V for both q-groups; each vf loaded once, used twice
    __builtin_amdgcn_s_setprio(1);
#pragma unroll
    for (int win = 0; win < 2; ++win) {
      int poff = q16 * 64 + (((win * 4 + g) ^ (q16 & 7)) * 8);
      short8 pfa = *(const short8*)(&sPa[w][poff]);
      short8 pfb = *(const short8*)(&sPb[w][poff]);
#pragma unroll
      for (int dt = 0; dt < 4; ++dt) {
        int d = dt * 16 + q16;
        short8 vf = *(const short8*)(&sV[cur][d * 64 + (((win * 4 + g) ^ (d & 7)) * 8)]);
        oa[dt] = __builtin_amdgcn_mfma_f32_16x16x32_bf16(pfa, vf, oa[dt], 0, 0, 0);
        ob[dt] = __builtin_amdgcn_mfma_f32_16x16x32_bf16(pfb, vf, ob[dt], 0, 0, 0);
      }
    }
    __builtin_amdgcn_s_setprio(0);

    asm volatile("s_waitcnt vmcnt(0)" ::: "memory");
    __syncthreads();
  }

  // epilogue: normalize, stage 32 rows through sPa/sPb, coalesced 16B stores
  float inva = 1.0f / suma, invb = 1.0f / sumb;
  int b = bh >> 4, h = bh & 15;
#pragma unroll
  for (int j = 0; j < 4; ++j) {
    float ija = __shfl(inva, g * 4 + j);
    float ijb = __shfl(invb, g * 4 + j);
#pragma unroll
    for (int dt = 0; dt < 4; ++dt) {
      sPa[w][(g * 4 + j) * 64 + dt * 16 + q16] = f2bf(oa[dt][j] * ija);
      sPb[w][(g * 4 + j) * 64 + dt * 16 + q16] = f2bf(ob[dt][j] * ijb);
    }
  }
  unsigned short* Ob = Oo + ((size_t)b * 2048 + q0) * 1024 + h * 64;
#pragma unroll
  for (int it = 0; it < 4; ++it) {
    int flat = it * 512 + l * 8;
    int r = flat >> 6, c = flat & 63;
    const unsigned short* src = (it < 2) ? &sPa[w][r * 64 + c] : &sPb[w][(r - 16) * 64 + c];
    *(u16x8*)(Ob + (size_t)r * 1024 + c) = *(const u16x8*)src;
  }
}

extern "C" void kernel_launch(void* const* d_in, const int* in_sizes, int n_in,
                              void* d_out, int out_size, void* d_ws, size_t ws_size,
                              hipStream_t stream) {
  const float* x = (const float*)d_in[0];
  const float* Wq = (const float*)d_in[1];
  const float* Wk = (const float*)d_in[2];
  const float* Wv = (const float*)d_in[3];
  const float* Wo = (const float*)d_in[4];
  const float* bo = (const float*)d_in[5];
  float* out = (float*)d_out;
  char* ws = (char*)d_ws;

  // workspace layout (bytes)
  unsigned short* xb    = (unsigned short*)(ws);               // 8192x1024 bf16 (16MB)
  unsigned short* wqkvT = (unsigned short*)(ws + 16777216);    // 3x1024x1024 (6MB)
  unsigned short* woT   = (unsigned short*)(ws + 23068672);    // 1024x1024 (2MB)
  unsigned short* qkv   = (unsigned short*)(ws + 25165824);    // Q,K: 2 x [64][2048][64]
  unsigned short* vT    = (unsigned short*)(ws + 75497472);    // [64][64][2048] (16MB)
  unsigned short* aout  = xb;  // reuse: xb dead after QKV GEMM

  k_prep<<<5120, 256, 0, stream>>>(x, Wq, Wk, Wv, Wo, xb, wqkvT, woT);
  k_gemm<0><<<1536, 256, 0, stream>>>(xb, wqkvT, qkv, vT, nullptr, nullptr);
  k_attn<<<512, 512, 0, stream>>>(qkv, qkv + 8388608, vT, aout);
  k_gemm<1><<<512, 256, 0, stream>>>(aout, woT, nullptr, nullptr, out, bo);
}